// Round 15
// baseline (3420.521 us; speedup 1.0000x reference)
//
#include <hip/hip_runtime.h>
#include <hip/hip_bf16.h>
#include <stdint.h>

typedef __bf16 bf16x8 __attribute__((ext_vector_type(8)));
typedef float  f32x4  __attribute__((ext_vector_type(4)));
typedef unsigned short ushort8v __attribute__((ext_vector_type(8)));

#define NH      4096
#define MB      1024
#define M2      2048
#define DIN     784
#define KPAD    832      /* 13*64 */
#define N_IN    8192
#define NLAYERS 24
#define NOUT    10

// GEMM geometry: 128x128 tile, BK=64, 4 waves (2M x 2N), 64x64/wave,
// 16x16x32 MFMA. A: LDS 3-ring (3 x 16 KB = 48 KB), vmcnt-slack pipeline.
// B: NO LDS — loaded directly global->VGPR from the XCD-local L2-resident W
// panel (register double-buffer bC/bN). Removes 96 KB/CU/tile of DS traffic;
// kernel flips from DS-bound to MFMA/L2-bound.
#define ASLE    8192                  /* elements per 16 KB A slot (128x64) */

__device__ __forceinline__ unsigned short f2bf(float x) {
  union { float f; unsigned u; } v; v.f = x;
  unsigned r = v.u + 0x7FFFu + ((v.u >> 16) & 1u);   // RNE (finite inputs)
  return (unsigned short)(r >> 16);
}
__device__ __forceinline__ float bf2f(unsigned short u) {
  union { unsigned u; float f; } v; v.u = ((unsigned)u) << 16; return v.f;
}

__device__ __forceinline__ void async16(const void* g, void* l) {
  __builtin_amdgcn_global_load_lds(
      (const __attribute__((address_space(1))) void*)g,
      (__attribute__((address_space(3))) void*)l, 16, 0, 0);
}

// ---------- weight conversion: fold o into W_sp ----------
__global__ void k_conv_wsp(const float* __restrict__ W, const float* __restrict__ o,
                           unsigned short* __restrict__ out) {
  size_t i = ((size_t)blockIdx.x * blockDim.x + threadIdx.x) * 4;
  if (i >= (size_t)NH * NH) return;
  float4 w = *reinterpret_cast<const float4*>(W + i);
  int k = (int)(i & (NH - 1));
  float4 ov = *reinterpret_cast<const float4*>(o + k);
  ushort4 r;
  r.x = f2bf(w.x * ov.x); r.y = f2bf(w.y * ov.y);
  r.z = f2bf(w.z * ov.z); r.w = f2bf(w.w * ov.w);
  *reinterpret_cast<ushort4*>(out + i) = r;
}

// ---------- fused pad+convert for W_in and x ----------
__global__ void k_conv_pad2(const float* __restrict__ Win, const float* __restrict__ x,
                            unsigned short* __restrict__ Win_bf,
                            unsigned short* __restrict__ X_bf) {
  size_t i = (size_t)blockIdx.x * blockDim.x + threadIdx.x;
  if (i >= (size_t)(N_IN + MB) * KPAD) return;
  int r = (int)(i / KPAD), c = (int)(i % KPAD);
  if (r < N_IN) Win_bf[i] = (c < DIN) ? f2bf(Win[(size_t)r * DIN + c]) : (unsigned short)0;
  else {
    int rr = r - N_IN;
    X_bf[(size_t)rr * KPAD + c] = (c < DIN) ? f2bf(x[(size_t)rr * DIN + c]) : (unsigned short)0;
  }
}

// ---------- GEMM core: A 3-ring LDS, B direct-to-register ----------
__device__ __forceinline__ void gemm_core(
    const unsigned short* __restrict__ Ag, const unsigned short* __restrict__ Bg,
    int K, int bm, int bn, unsigned short* lds, f32x4 acc[4][4])
{
  const int t    = threadIdx.x;
  const int lane = t & 63;
  const int wave = t >> 6;           // 0..3
  const int wm   = wave >> 1;        // 64-row band
  const int wn   = wave & 1;         // 64-col band
  const int l15  = lane & 15;
  const int lkb  = (lane >> 4) * 16; // byte offset of k-group within row
  const int lke  = (lane >> 4) * 8;  // element offset of k-group

  // ---- A staging: linear LDS dest, pre-swizzled global source ----
  const int srow = t >> 3;
  const int sb   = ((t & 7) * 16) ^ ((srow & 7) << 4);
  const unsigned aG0 = (unsigned)((bm + srow) * K + (sb >> 1));

  auto STAGE_A = [&](int sA, int k0) {             // 4 async16/thread
    unsigned short* s = lds + sA * ASLE;
#pragma unroll
    for (int j = 0; j < 4; ++j)
      async16(Ag + aG0 + (unsigned)(j * 32 * K + k0), s + t * 8 + j * 2048);
  };

  // ---- A fragment LDS read offsets (swizzled) ----
  int aRd[2][4];
#pragma unroll
  for (int kk = 0; kk < 2; ++kk)
#pragma unroll
    for (int i = 0; i < 4; ++i) {
      const int ra = wm * 64 + i * 16 + l15;
      aRd[kk][i] = (ra * 128 + ((kk * 64 + lkb) ^ ((ra & 7) << 4))) >> 1;
    }

  // ---- B fragment global element offsets (per-lane, L2-resident W panel) ----
  unsigned bOffE[2][4];
#pragma unroll
  for (int kk = 0; kk < 2; ++kk)
#pragma unroll
    for (int i = 0; i < 4; ++i)
      bOffE[kk][i] = (unsigned)((bn + wn * 64 + i * 16 + l15) * K + kk * 32 + lke);

  bf16x8 bC[2][4], bN[2][4];

  const int nt = K >> 6;
  // prologue: B(0) regs [8 loads], A(0), A(1) staged [8 loads]
#pragma unroll
  for (int kk = 0; kk < 2; ++kk)
#pragma unroll
    for (int i = 0; i < 4; ++i)
      bC[kk][i] = *reinterpret_cast<const bf16x8*>(Bg + bOffE[kk][i]);
  STAGE_A(0, 0);
  if (nt > 1) {
    STAGE_A(1, 64);
    asm volatile("s_waitcnt vmcnt(4)" ::: "memory");   // B(0)+A(0) done, A(1) rides
  } else {
    asm volatile("s_waitcnt vmcnt(0)" ::: "memory");
  }
  __builtin_amdgcn_s_barrier();

  int sA = 0, sA2 = 2;               // kt%3, (kt+2)%3
  for (int kt = 0; kt < nt; ++kt) {
    // issue next-tile B loads (global->reg), then next+1 A stage
    if (kt + 1 < nt) {
      const unsigned ka = (unsigned)((kt + 1) << 6);
#pragma unroll
      for (int kk = 0; kk < 2; ++kk)
#pragma unroll
        for (int i = 0; i < 4; ++i)
          bN[kk][i] = *reinterpret_cast<const bf16x8*>(Bg + bOffE[kk][i] + ka);
    }
    if (kt + 2 < nt) STAGE_A(sA2, (kt + 2) << 6);
    // A fragments for this tile (one ds_read burst)
    const unsigned short* baseA = lds + sA * ASLE;
    bf16x8 a[2][4];
#pragma unroll
    for (int kk = 0; kk < 2; ++kk)
#pragma unroll
      for (int i = 0; i < 4; ++i)
        a[kk][i] = *reinterpret_cast<const bf16x8*>(baseA + aRd[kk][i]);
    // one 32-MFMA cluster
    __builtin_amdgcn_s_setprio(1);
#pragma unroll
    for (int kk = 0; kk < 2; ++kk)
#pragma unroll
      for (int mi = 0; mi < 4; ++mi)
#pragma unroll
        for (int ni = 0; ni < 4; ++ni)
          acc[mi][ni] = __builtin_amdgcn_mfma_f32_16x16x32_bf16(a[kk][mi], bC[kk][ni], acc[mi][ni], 0, 0, 0);
    __builtin_amdgcn_s_setprio(0);
    if (kt + 1 < nt) {
      // bC <- bN (dependency forces compiler wait on B(kt+1); A(kt+2) rides)
#pragma unroll
      for (int kk = 0; kk < 2; ++kk)
#pragma unroll
        for (int i = 0; i < 4; ++i)
          bC[kk][i] = bN[kk][i];
      if (kt + 2 < nt) asm volatile("s_waitcnt vmcnt(4)" ::: "memory");  // A(kt+1)+B(kt+1) done
      else             asm volatile("s_waitcnt vmcnt(0)" ::: "memory");
      __builtin_amdgcn_s_barrier();              // A slot (kt+1) globally ready
    }
    sA  = (sA  == 2) ? 0 : sA  + 1;
    sA2 = (sA2 == 2) ? 0 : sA2 + 1;
  }
}

// ---------- recurrent layer GEMM ----------
__global__ __launch_bounds__(256, 2) void k_gemm_layer(
    const unsigned short* __restrict__ A, const unsigned short* __restrict__ W,
    const float* __restrict__ bias, float* __restrict__ preact,
    unsigned short* __restrict__ Anext)
{
  __shared__ __align__(16) unsigned short lds[3 * ASLE];   // 48 KB
  const int bid = blockIdx.x;            // 512 blocks = 16 bm x 32 bn
  const int xcd = bid & 7;
  const int idx = bid >> 3;              // 0..63
  const int bm  = (idx >> 2) * 128;      // 16 m-bands
  const int bn  = (xcd * 4 + (idx & 3)) * 128;   // XCD owns 4 bn-bands (W L2-fit)
  f32x4 acc[4][4] = {};
  gemm_core(A, W, NH, bm, bn, lds, acc);

  const int lane = threadIdx.x & 63;
  const int wave = threadIdx.x >> 6;
  const int wm = (wave >> 1) * 64, wn = (wave & 1) * 64;
  const int l15 = lane & 15;
#pragma unroll
  for (int mi = 0; mi < 4; ++mi) {
    const int gm0 = bm + wm + mi * 16 + (lane >> 4) * 4;   // C/D: row=(lane>>4)*4+r
#pragma unroll
    for (int ni = 0; ni < 4; ++ni) {
      const int gn = bn + wn + ni * 16 + l15;              // C/D: col=lane&15
      const float bv = bias[gn];
#pragma unroll
      for (int r = 0; r < 4; ++r) {
        const int gm = gm0 + r;
        const float y = acc[mi][ni][r] + bv;
        if (gm < MB) preact[(size_t)gm * NH + gn] = y;
        Anext[(size_t)gm * NH + gn] = f2bf(y > 0.f ? y : 0.f);
      }
    }
  }
}

// ---------- input GEMM ----------
__global__ __launch_bounds__(256, 2) void k_gemm_in(
    const unsigned short* __restrict__ X, const unsigned short* __restrict__ W,
    const float* __restrict__ bias, float* __restrict__ preact0,
    unsigned short* __restrict__ A0)
{
  __shared__ __align__(16) unsigned short lds[3 * ASLE];
  const int bid = blockIdx.x;            // 512 blocks = 8 bm x 64 bn
  const int xcd = bid & 7;
  const int idx = bid >> 3;              // 0..63
  const int bm  = (idx >> 3) * 128;      // 8 m-bands
  const int bn  = (xcd * 8 + (idx & 7)) * 128;
  f32x4 acc[4][4] = {};
  gemm_core(X, W, KPAD, bm, bn, lds, acc);

  const int lane = threadIdx.x & 63;
  const int wave = threadIdx.x >> 6;
  const int wm = (wave >> 1) * 64, wn = (wave & 1) * 64;
  const int l15 = lane & 15;
#pragma unroll
  for (int mi = 0; mi < 4; ++mi) {
    const int gm0 = bm + wm + mi * 16 + (lane >> 4) * 4;
#pragma unroll
    for (int ni = 0; ni < 4; ++ni) {
      const int gn = bn + wn + ni * 16 + l15;
      const float bv = bias[gn];
#pragma unroll
      for (int r = 0; r < 4; ++r) {
        const int gm = gm0 + r;
        const float y = acc[mi][ni][r] + bv;
        const unsigned short rl = f2bf(y > 0.f ? y : 0.f);
        if (gn < NH) {                       // "a" stream
          preact0[(size_t)gm * NH + gn] = y;
          A0[(size_t)gm * NH + gn] = rl;
        } else {                             // "b" stream -> rows 1024..2047
          A0[(size_t)(MB + gm) * NH + (gn - NH)] = rl;
        }
      }
    }
  }
}

// ---------- final head: 256 blocks x 8 rows, vectorized loads ----------
__global__ __launch_bounds__(256) void k_final(
    const unsigned short* __restrict__ A, const float* __restrict__ Wf,
    const float* __restrict__ of, const float* __restrict__ bf_,
    float* __restrict__ out)
{
  __shared__ float red[4][NOUT];
  const int t = threadIdx.x;
  for (int rr = 0; rr < 8; ++rr) {
    const int m = blockIdx.x * 8 + rr;          // 0..2047
    float accj[NOUT];
#pragma unroll
    for (int j = 0; j < NOUT; ++j) accj[j] = 0.f;
    for (int k0 = t * 8; k0 < NH; k0 += 256 * 8) {
      const ushort8v av = *reinterpret_cast<const ushort8v*>(A + (size_t)m * NH + k0);
      const float4 o0 = *reinterpret_cast<const float4*>(of + k0);
      const float4 o1 = *reinterpret_cast<const float4*>(of + k0 + 4);
      float a[8];
      a[0] = bf2f(av[0]) * o0.x; a[1] = bf2f(av[1]) * o0.y;
      a[2] = bf2f(av[2]) * o0.z; a[3] = bf2f(av[3]) * o0.w;
      a[4] = bf2f(av[4]) * o1.x; a[5] = bf2f(av[5]) * o1.y;
      a[6] = bf2f(av[6]) * o1.z; a[7] = bf2f(av[7]) * o1.w;
#pragma unroll
      for (int j = 0; j < NOUT; ++j) {
        const float4 w0 = *reinterpret_cast<const float4*>(Wf + (size_t)j * NH + k0);
        const float4 w1 = *reinterpret_cast<const float4*>(Wf + (size_t)j * NH + k0 + 4);
        accj[j] += a[0]*w0.x + a[1]*w0.y + a[2]*w0.z + a[3]*w0.w
                 + a[4]*w1.x + a[5]*w1.y + a[6]*w1.z + a[7]*w1.w;
      }
    }
#pragma unroll
    for (int j = 0; j < NOUT; ++j) {
      float v = accj[j];
      for (int off = 32; off > 0; off >>= 1) v += __shfl_down(v, off);
      if ((t & 63) == 0) red[t >> 6][j] = v;
    }
    __syncthreads();
    if (t < NOUT)
      out[(size_t)m * NOUT + t] = red[0][t] + red[1][t] + red[2][t] + red[3][t] + bf_[t];
    __syncthreads();
  }
}

extern "C" void kernel_launch(void* const* d_in, const int* in_sizes, int n_in,
                              void* d_out, int out_size, void* d_ws, size_t ws_size,
                              hipStream_t stream) {
  const float* x     = (const float*)d_in[0];
  const float* W_in  = (const float*)d_in[1];
  const float* b_in  = (const float*)d_in[2];
  const float* keysp = (const float*)d_in[3];
  const float* W_sp  = (const float*)d_in[4];
  const float* b_sp  = (const float*)d_in[5];
  const float* keyf  = (const float*)d_in[6];
  const float* W_f   = (const float*)d_in[7];
  const float* b_f   = (const float*)d_in[8];

  float* out    = (float*)d_out;
  float* preact = out + (size_t)2 * MB * NOUT;  // 25 x 1024 x 4096

  char* ws = (char*)d_ws;
  unsigned short* Wsp_bf = (unsigned short*)ws;  ws += (size_t)NH * NH * 2;
  unsigned short* A0     = (unsigned short*)ws;  ws += (size_t)M2 * NH * 2;
  unsigned short* A1     = (unsigned short*)ws;  ws += (size_t)M2 * NH * 2;
  unsigned short* Win_bf = (unsigned short*)ws;  ws += (size_t)N_IN * KPAD * 2;
  unsigned short* X_bf   = (unsigned short*)ws;  ws += (size_t)MB * KPAD * 2;

  k_conv_wsp<<<(NH * (size_t)NH / 4 + 255) / 256, 256, 0, stream>>>(W_sp, keysp, Wsp_bf);
  k_conv_pad2<<<((size_t)(N_IN + MB) * KPAD + 255) / 256, 256, 0, stream>>>(
      W_in, x, Win_bf, X_bf);

  // input GEMM: M=1024, N=8192, K=832 -> 8*64 = 512 blocks
  k_gemm_in<<<512, 256, 0, stream>>>(X_bf, Win_bf, b_in, preact, A0);

  // 24 recurrent layers: M=2048, N=4096, K=4096 -> 16*32 = 512 blocks
  unsigned short* Ain = A0;
  unsigned short* Aout = A1;
  for (int tlay = 0; tlay < NLAYERS; ++tlay) {
    float* pre = preact + (size_t)(tlay + 1) * MB * NH;
    k_gemm_layer<<<512, 256, 0, stream>>>(Ain, Wsp_bf, b_sp, pre, Aout);
    unsigned short* tmp = Ain; Ain = Aout; Aout = tmp;
  }

  k_final<<<M2 / 8, 256, 0, stream>>>(Ain, W_f, keyf, b_f, out);
}

// Round 16
// 1698.815 us; speedup vs baseline: 2.0135x; 2.0135x over previous
//
#include <hip/hip_runtime.h>
#include <hip/hip_bf16.h>
#include <stdint.h>

typedef __bf16 bf16x8 __attribute__((ext_vector_type(8)));
typedef float  f32x4  __attribute__((ext_vector_type(4)));
typedef unsigned short ushort8v __attribute__((ext_vector_type(8)));

#define NH      4096
#define MB      1024
#define M2      2048
#define DIN     784
#define KPAD    832      /* 13*64 */
#define N_IN    8192
#define NLAYERS 24
#define NOUT    10

// GEMM: 128x128 tile, BK=64, 4 waves (2M x 2N), 64x64/wave, 16x16x32 MFMA.
// A: LDS 3-ring (48 KB), vmcnt-slack pipeline (R14).
// B: NO LDS — W is PRE-ARRANGED in MFMA-fragment order W'[bnb][kt][c][lane][8]
// (c = wn*8+kk*4+i), so per-lane B loads are fully coalesced global->VGPR
// (1 KB/instr). DS traffic/block-tile 96->48 KB => MFMA-bound.
#define ASLE    8192                  /* elements per 16 KB A slot (128x64) */
#define WSP_BNB_STRIDE  (64 * 16 * 64 * 8)   /* 524288 elems per bnb (K=4096) */
#define WIN_BNB_STRIDE  (13 * 16 * 64 * 8)   /* 106496 elems per bnb (K=832) */

__device__ __forceinline__ unsigned short f2bf(float x) {
  union { float f; unsigned u; } v; v.f = x;
  unsigned r = v.u + 0x7FFFu + ((v.u >> 16) & 1u);   // RNE (finite inputs)
  return (unsigned short)(r >> 16);
}
__device__ __forceinline__ float bf2f(unsigned short u) {
  union { unsigned u; float f; } v; v.u = ((unsigned)u) << 16; return v.f;
}

__device__ __forceinline__ void async16(const void* g, void* l) {
  __builtin_amdgcn_global_load_lds(
      (const __attribute__((address_space(1))) void*)g,
      (__attribute__((address_space(3))) void*)l, 16, 0, 0);
}

// ---------- W_sp -> fragment-order bf16 (with key fold), via LDS transpose ----------
__global__ __launch_bounds__(256) void k_conv_wspf(
    const float* __restrict__ W, const float* __restrict__ o,
    unsigned short* __restrict__ out)
{
  __shared__ unsigned short tile[128 * 64];
  const int bnb = blockIdx.x & 31;     // W row-block (output col-block)
  const int kt  = blockIdx.x >> 5;     // 0..63
  const int t   = threadIdx.x;
#pragma unroll
  for (int j = 0; j < 8; ++j) {        // coalesced load + convert
    const int idx = j * 1024 + t * 4;  // 0..8191
    const int row = idx >> 6, kc = idx & 63;
    const float4 w  = *reinterpret_cast<const float4*>(W + (size_t)(bnb * 128 + row) * NH + kt * 64 + kc);
    const float4 ov = *reinterpret_cast<const float4*>(o + kt * 64 + kc);
    ushort4 r;
    r.x = f2bf(w.x * ov.x); r.y = f2bf(w.y * ov.y);
    r.z = f2bf(w.z * ov.z); r.w = f2bf(w.w * ov.w);
    *reinterpret_cast<ushort4*>(tile + idx) = r;
  }
  __syncthreads();
  unsigned short* dst = out + ((size_t)bnb * 64 + kt) * (16 * 64 * 8);
#pragma unroll
  for (int j = 0; j < 4; ++j) {        // fragment-order store (coalesced)
    const int ch = j * 256 + t;        // (c,l)
    const int c = ch >> 6, l = ch & 63;
    const int wn = c >> 3, kk = (c >> 2) & 1, i = c & 3;
    const int row = wn * 64 + i * 16 + (l & 15);
    const int kc  = kk * 32 + (l >> 4) * 8;
    *reinterpret_cast<ushort8v*>(dst + (size_t)ch * 8) =
        *reinterpret_cast<const ushort8v*>(tile + row * 64 + kc);
  }
}

// ---------- W_in -> fragment-order bf16 (K padded to 832) ----------
__global__ __launch_bounds__(256) void k_conv_winf(
    const float* __restrict__ W, unsigned short* __restrict__ out)
{
  __shared__ unsigned short tile[128 * 64];
  const int bnb = blockIdx.x & 63;     // 0..63
  const int kt  = blockIdx.x >> 6;     // 0..12
  const int t   = threadIdx.x;
#pragma unroll
  for (int j = 0; j < 8; ++j) {
    const int idx = j * 1024 + t * 4;
    const int row = idx >> 6, kc = idx & 63;
    const int k = kt * 64 + kc;
    ushort4 r;
    if (k < DIN) {
      const float4 w = *reinterpret_cast<const float4*>(W + (size_t)(bnb * 128 + row) * DIN + k);
      r.x = f2bf(w.x); r.y = f2bf(w.y); r.z = f2bf(w.z); r.w = f2bf(w.w);
    } else {
      r.x = r.y = r.z = r.w = 0;
    }
    *reinterpret_cast<ushort4*>(tile + idx) = r;
  }
  __syncthreads();
  unsigned short* dst = out + ((size_t)bnb * 13 + kt) * (16 * 64 * 8);
#pragma unroll
  for (int j = 0; j < 4; ++j) {
    const int ch = j * 256 + t;
    const int c = ch >> 6, l = ch & 63;
    const int wn = c >> 3, kk = (c >> 2) & 1, i = c & 3;
    const int row = wn * 64 + i * 16 + (l & 15);
    const int kc  = kk * 32 + (l >> 4) * 8;
    *reinterpret_cast<ushort8v*>(dst + (size_t)ch * 8) =
        *reinterpret_cast<const ushort8v*>(tile + row * 64 + kc);
  }
}

// ---------- x -> bf16 row-major KPAD ----------
__global__ void k_conv_x(const float* __restrict__ x, unsigned short* __restrict__ X_bf) {
  size_t i = (size_t)blockIdx.x * blockDim.x + threadIdx.x;
  if (i >= (size_t)MB * KPAD) return;
  int r = (int)(i / KPAD), c = (int)(i % KPAD);
  X_bf[i] = (c < DIN) ? f2bf(x[(size_t)r * DIN + c]) : (unsigned short)0;
}

// ---------- GEMM core: A 3-ring LDS, B fragment-order direct-to-register ----------
__device__ __forceinline__ void gemm_core(
    const unsigned short* __restrict__ Ag, const unsigned short* __restrict__ Bp,
    int K, int bm, unsigned short* lds, f32x4 acc[4][4])
{
  const int t    = threadIdx.x;
  const int lane = t & 63;
  const int wave = t >> 6;           // 0..3
  const int wm   = wave >> 1;        // 64-row band
  const int wn   = wave & 1;         // 64-col band
  const int l15  = lane & 15;
  const int lkb  = (lane >> 4) * 16; // byte offset of k-group within row

  // ---- A staging: linear LDS dest, pre-swizzled global source ----
  const int srow = t >> 3;
  const int sb   = ((t & 7) * 16) ^ ((srow & 7) << 4);
  const unsigned aG0 = (unsigned)((bm + srow) * K + (sb >> 1));

  auto STAGE_A = [&](int sA, int k0) {             // 4 async16/thread
    unsigned short* s = lds + sA * ASLE;
#pragma unroll
    for (int j = 0; j < 4; ++j)
      async16(Ag + aG0 + (unsigned)(j * 32 * K + k0), s + t * 8 + j * 2048);
  };

  // ---- A fragment LDS read offsets (swizzled) ----
  int aRd[2][4];
#pragma unroll
  for (int kk = 0; kk < 2; ++kk)
#pragma unroll
    for (int i = 0; i < 4; ++i) {
      const int ra = wm * 64 + i * 16 + l15;
      aRd[kk][i] = (ra * 128 + ((kk * 64 + lkb) ^ ((ra & 7) << 4))) >> 1;
    }

  // ---- B: fragment-order chunks; coalesced per-lane 16B loads ----
  const unsigned bBase = (unsigned)((wn * 8) * 512 + lane * 8);   // + kt*8192 + j*512

  bf16x8 bC[2][4], bN[2][4];

  const int nt = K >> 6;
  // prologue: B(0) regs [8 loads], A(0), A(1) staged
#pragma unroll
  for (int j = 0; j < 8; ++j)
    bC[j >> 2][j & 3] = *reinterpret_cast<const bf16x8*>(Bp + bBase + (unsigned)(j * 512));
  STAGE_A(0, 0);
  if (nt > 1) {
    STAGE_A(1, 64);
    asm volatile("s_waitcnt vmcnt(4)" ::: "memory");   // B(0)+A(0) done, A(1) rides
  } else {
    asm volatile("s_waitcnt vmcnt(0)" ::: "memory");
  }
  __builtin_amdgcn_s_barrier();

  int sA = 0, sA2 = 2;               // kt%3, (kt+2)%3
  for (int kt = 0; kt < nt; ++kt) {
    if (kt + 1 < nt) {
      const unsigned kb = bBase + (unsigned)((kt + 1) * 8192);
#pragma unroll
      for (int j = 0; j < 8; ++j)
        bN[j >> 2][j & 3] = *reinterpret_cast<const bf16x8*>(Bp + kb + (unsigned)(j * 512));
    }
    if (kt + 2 < nt) STAGE_A(sA2, (kt + 2) << 6);
    // A fragments for this tile (one ds_read burst)
    const unsigned short* baseA = lds + sA * ASLE;
    bf16x8 a[2][4];
#pragma unroll
    for (int kk = 0; kk < 2; ++kk)
#pragma unroll
      for (int i = 0; i < 4; ++i)
        a[kk][i] = *reinterpret_cast<const bf16x8*>(baseA + aRd[kk][i]);
    // one 32-MFMA cluster
    __builtin_amdgcn_s_setprio(1);
#pragma unroll
    for (int kk = 0; kk < 2; ++kk)
#pragma unroll
      for (int mi = 0; mi < 4; ++mi)
#pragma unroll
        for (int ni = 0; ni < 4; ++ni)
          acc[mi][ni] = __builtin_amdgcn_mfma_f32_16x16x32_bf16(a[kk][mi], bC[kk][ni], acc[mi][ni], 0, 0, 0);
    __builtin_amdgcn_s_setprio(0);
    if (kt + 1 < nt) {
      // retire A(kt+1)+B(kt+1); A(kt+2) rides across the barrier
      if (kt + 2 < nt) asm volatile("s_waitcnt vmcnt(4)" ::: "memory");
      else             asm volatile("s_waitcnt vmcnt(0)" ::: "memory");
#pragma unroll
      for (int kk = 0; kk < 2; ++kk)
#pragma unroll
        for (int i = 0; i < 4; ++i)
          bC[kk][i] = bN[kk][i];
      __builtin_amdgcn_s_barrier();              // A slot (kt+1) globally ready
    }
    sA  = (sA  == 2) ? 0 : sA  + 1;
    sA2 = (sA2 == 2) ? 0 : sA2 + 1;
  }
}

// ---------- recurrent layer GEMM ----------
__global__ __launch_bounds__(256, 2) void k_gemm_layer(
    const unsigned short* __restrict__ A, const unsigned short* __restrict__ Wf_,
    const float* __restrict__ bias, float* __restrict__ preact,
    unsigned short* __restrict__ Anext)
{
  __shared__ __align__(16) unsigned short lds[3 * ASLE];   // 48 KB
  const int bid = blockIdx.x;            // 512 blocks = 16 bm x 32 bn
  const int xcd = bid & 7;
  const int idx = bid >> 3;              // 0..63
  const int bm  = (idx >> 2) * 128;      // 16 m-bands
  const int bn  = (xcd * 4 + (idx & 3)) * 128;   // XCD owns 4 bn-bands (W L2-fit)
  f32x4 acc[4][4] = {};
  gemm_core(A, Wf_ + (size_t)(bn >> 7) * WSP_BNB_STRIDE, NH, bm, lds, acc);

  const int lane = threadIdx.x & 63;
  const int wave = threadIdx.x >> 6;
  const int wm = (wave >> 1) * 64, wn = (wave & 1) * 64;
  const int l15 = lane & 15;
#pragma unroll
  for (int mi = 0; mi < 4; ++mi) {
    const int gm0 = bm + wm + mi * 16 + (lane >> 4) * 4;   // C/D: row=(lane>>4)*4+r
#pragma unroll
    for (int ni = 0; ni < 4; ++ni) {
      const int gn = bn + wn + ni * 16 + l15;              // C/D: col=lane&15
      const float bv = bias[gn];
#pragma unroll
      for (int r = 0; r < 4; ++r) {
        const int gm = gm0 + r;
        const float y = acc[mi][ni][r] + bv;
        if (gm < MB) preact[(size_t)gm * NH + gn] = y;
        Anext[(size_t)gm * NH + gn] = f2bf(y > 0.f ? y : 0.f);
      }
    }
  }
}

// ---------- input GEMM ----------
__global__ __launch_bounds__(256, 2) void k_gemm_in(
    const unsigned short* __restrict__ X, const unsigned short* __restrict__ Wf_,
    const float* __restrict__ bias, float* __restrict__ preact0,
    unsigned short* __restrict__ A0)
{
  __shared__ __align__(16) unsigned short lds[3 * ASLE];
  const int bid = blockIdx.x;            // 512 blocks = 8 bm x 64 bn
  const int xcd = bid & 7;
  const int idx = bid >> 3;              // 0..63
  const int bm  = (idx >> 3) * 128;      // 8 m-bands
  const int bn  = (xcd * 8 + (idx & 7)) * 128;
  f32x4 acc[4][4] = {};
  gemm_core(X, Wf_ + (size_t)(bn >> 7) * WIN_BNB_STRIDE, KPAD, bm, lds, acc);

  const int lane = threadIdx.x & 63;
  const int wave = threadIdx.x >> 6;
  const int wm = (wave >> 1) * 64, wn = (wave & 1) * 64;
  const int l15 = lane & 15;
#pragma unroll
  for (int mi = 0; mi < 4; ++mi) {
    const int gm0 = bm + wm + mi * 16 + (lane >> 4) * 4;
#pragma unroll
    for (int ni = 0; ni < 4; ++ni) {
      const int gn = bn + wn + ni * 16 + l15;
      const float bv = bias[gn];
#pragma unroll
      for (int r = 0; r < 4; ++r) {
        const int gm = gm0 + r;
        const float y = acc[mi][ni][r] + bv;
        const unsigned short rl = f2bf(y > 0.f ? y : 0.f);
        if (gn < NH) {                       // "a" stream
          preact0[(size_t)gm * NH + gn] = y;
          A0[(size_t)gm * NH + gn] = rl;
        } else {                             // "b" stream -> rows 1024..2047
          A0[(size_t)(MB + gm) * NH + (gn - NH)] = rl;
        }
      }
    }
  }
}

// ---------- final head: 256 blocks x 8 rows, vectorized loads ----------
__global__ __launch_bounds__(256) void k_final(
    const unsigned short* __restrict__ A, const float* __restrict__ Wf,
    const float* __restrict__ of, const float* __restrict__ bf_,
    float* __restrict__ out)
{
  __shared__ float red[4][NOUT];
  const int t = threadIdx.x;
  for (int rr = 0; rr < 8; ++rr) {
    const int m = blockIdx.x * 8 + rr;          // 0..2047
    float accj[NOUT];
#pragma unroll
    for (int j = 0; j < NOUT; ++j) accj[j] = 0.f;
    for (int k0 = t * 8; k0 < NH; k0 += 256 * 8) {
      const ushort8v av = *reinterpret_cast<const ushort8v*>(A + (size_t)m * NH + k0);
      const float4 o0 = *reinterpret_cast<const float4*>(of + k0);
      const float4 o1 = *reinterpret_cast<const float4*>(of + k0 + 4);
      float a[8];
      a[0] = bf2f(av[0]) * o0.x; a[1] = bf2f(av[1]) * o0.y;
      a[2] = bf2f(av[2]) * o0.z; a[3] = bf2f(av[3]) * o0.w;
      a[4] = bf2f(av[4]) * o1.x; a[5] = bf2f(av[5]) * o1.y;
      a[6] = bf2f(av[6]) * o1.z; a[7] = bf2f(av[7]) * o1.w;
#pragma unroll
      for (int j = 0; j < NOUT; ++j) {
        const float4 w0 = *reinterpret_cast<const float4*>(Wf + (size_t)j * NH + k0);
        const float4 w1 = *reinterpret_cast<const float4*>(Wf + (size_t)j * NH + k0 + 4);
        accj[j] += a[0]*w0.x + a[1]*w0.y + a[2]*w0.z + a[3]*w0.w
                 + a[4]*w1.x + a[5]*w1.y + a[6]*w1.z + a[7]*w1.w;
      }
    }
#pragma unroll
    for (int j = 0; j < NOUT; ++j) {
      float v = accj[j];
      for (int off = 32; off > 0; off >>= 1) v += __shfl_down(v, off);
      if ((t & 63) == 0) red[t >> 6][j] = v;
    }
    __syncthreads();
    if (t < NOUT)
      out[(size_t)m * NOUT + t] = red[0][t] + red[1][t] + red[2][t] + red[3][t] + bf_[t];
    __syncthreads();
  }
}

extern "C" void kernel_launch(void* const* d_in, const int* in_sizes, int n_in,
                              void* d_out, int out_size, void* d_ws, size_t ws_size,
                              hipStream_t stream) {
  const float* x     = (const float*)d_in[0];
  const float* W_in  = (const float*)d_in[1];
  const float* b_in  = (const float*)d_in[2];
  const float* keysp = (const float*)d_in[3];
  const float* W_sp  = (const float*)d_in[4];
  const float* b_sp  = (const float*)d_in[5];
  const float* keyf  = (const float*)d_in[6];
  const float* W_f   = (const float*)d_in[7];
  const float* b_f   = (const float*)d_in[8];

  float* out    = (float*)d_out;
  float* preact = out + (size_t)2 * MB * NOUT;  // 25 x 1024 x 4096

  char* ws = (char*)d_ws;
  unsigned short* Wsp_f  = (unsigned short*)ws;  ws += (size_t)NH * NH * 2;
  unsigned short* A0     = (unsigned short*)ws;  ws += (size_t)M2 * NH * 2;
  unsigned short* A1     = (unsigned short*)ws;  ws += (size_t)M2 * NH * 2;
  unsigned short* Win_f  = (unsigned short*)ws;  ws += (size_t)N_IN * KPAD * 2;
  unsigned short* X_bf   = (unsigned short*)ws;  ws += (size_t)MB * KPAD * 2;

  k_conv_wspf<<<32 * 64, 256, 0, stream>>>(W_sp, keysp, Wsp_f);
  k_conv_winf<<<64 * 13, 256, 0, stream>>>(W_in, Win_f);
  k_conv_x<<<((size_t)MB * KPAD + 255) / 256, 256, 0, stream>>>(x, X_bf);

  // input GEMM: M=1024, N=8192, K=832 -> 8*64 = 512 blocks
  k_gemm_in<<<512, 256, 0, stream>>>(X_bf, Win_f, b_in, preact, A0);

  // 24 recurrent layers: M=2048, N=4096, K=4096 -> 16*32 = 512 blocks
  unsigned short* Ain = A0;
  unsigned short* Aout = A1;
  for (int tlay = 0; tlay < NLAYERS; ++tlay) {
    float* pre = preact + (size_t)(tlay + 1) * MB * NH;
    k_gemm_layer<<<512, 256, 0, stream>>>(Ain, Wsp_f, b_sp, pre, Aout);
    unsigned short* tmp = Ain; Ain = Aout; Aout = tmp;
  }

  k_final<<<M2 / 8, 256, 0, stream>>>(Ain, W_f, keyf, b_f, out);
}

// Round 17
// 1514.680 us; speedup vs baseline: 2.2582x; 1.1216x over previous
//
#include <hip/hip_runtime.h>
#include <hip/hip_bf16.h>
#include <stdint.h>

typedef __bf16 bf16x8 __attribute__((ext_vector_type(8)));
typedef float  f32x4  __attribute__((ext_vector_type(4)));
typedef unsigned short ushort8v __attribute__((ext_vector_type(8)));

#define NH      4096
#define MB      1024
#define M2      2048
#define DIN     784
#define KPAD    832      /* 13*64 */
#define N_IN    8192
#define NLAYERS 24
#define NOUT    10

// GEMM geometry (R14 best): 128x128 tile, BK=64, 4 waves (2M x 2N), 64x64/wave,
// 16x16x32 MFMA. LDS: asymmetric rings — A 3-deep (slow operand, HBM/L3),
// B 2-deep (W panel, L2-resident) = 5 x 16 KB = 80 KB -> exactly 2 blocks/CU.
// Steady-state wait vmcnt(4) retires A(kt)+B(kt), keeps A(kt+1) in flight ->
// no full drain at tile boundaries; one barrier per tile. Full-preload interior.
#define ASLE    8192                  /* elements per 16 KB slot (128x64) */
#define BOFF    (3 * ASLE)            /* B slots start after 3 A slots */

__device__ __forceinline__ unsigned short f2bf(float x) {
  union { float f; unsigned u; } v; v.f = x;
  unsigned r = v.u + 0x7FFFu + ((v.u >> 16) & 1u);   // RNE (finite inputs)
  return (unsigned short)(r >> 16);
}
__device__ __forceinline__ float bf2f(unsigned short u) {
  union { unsigned u; float f; } v; v.u = ((unsigned)u) << 16; return v.f;
}

__device__ __forceinline__ void async16(const void* g, void* l) {
  __builtin_amdgcn_global_load_lds(
      (const __attribute__((address_space(1))) void*)g,
      (__attribute__((address_space(3))) void*)l, 16, 0, 0);
}

// ---------- weight conversion: fold o into W_sp ----------
__global__ void k_conv_wsp(const float* __restrict__ W, const float* __restrict__ o,
                           unsigned short* __restrict__ out) {
  size_t i = ((size_t)blockIdx.x * blockDim.x + threadIdx.x) * 4;
  if (i >= (size_t)NH * NH) return;
  float4 w = *reinterpret_cast<const float4*>(W + i);
  int k = (int)(i & (NH - 1));
  float4 ov = *reinterpret_cast<const float4*>(o + k);
  ushort4 r;
  r.x = f2bf(w.x * ov.x); r.y = f2bf(w.y * ov.y);
  r.z = f2bf(w.z * ov.z); r.w = f2bf(w.w * ov.w);
  *reinterpret_cast<ushort4*>(out + i) = r;
}

// ---------- fused pad+convert for W_in and x ----------
__global__ void k_conv_pad2(const float* __restrict__ Win, const float* __restrict__ x,
                            unsigned short* __restrict__ Win_bf,
                            unsigned short* __restrict__ X_bf) {
  size_t i = (size_t)blockIdx.x * blockDim.x + threadIdx.x;
  if (i >= (size_t)(N_IN + MB) * KPAD) return;
  int r = (int)(i / KPAD), c = (int)(i % KPAD);
  if (r < N_IN) Win_bf[i] = (c < DIN) ? f2bf(Win[(size_t)r * DIN + c]) : (unsigned short)0;
  else {
    int rr = r - N_IN;
    X_bf[(size_t)rr * KPAD + c] = (c < DIN) ? f2bf(x[(size_t)rr * DIN + c]) : (unsigned short)0;
  }
}

// ---------- 128x128 GEMM core: A 3-ring / B 2-ring, vmcnt(4) steady ----------
__device__ __forceinline__ void gemm_core(
    const unsigned short* __restrict__ Ag, const unsigned short* __restrict__ Bg,
    int K, int bm, int bn, unsigned short* lds, f32x4 acc[4][4])
{
  const int t    = threadIdx.x;
  const int lane = t & 63;
  const int wave = t >> 6;           // 0..3
  const int wm   = wave >> 1;        // 64-row band
  const int wn   = wave & 1;         // 64-col band
  const int l15  = lane & 15;
  const int lkb  = (lane >> 4) * 16; // byte offset of k-group within row

  const int srow = t >> 3;
  const int sb   = ((t & 7) * 16) ^ ((srow & 7) << 4);
  const unsigned aG0 = (unsigned)((bm + srow) * K + (sb >> 1));
  const unsigned bG0 = (unsigned)((bn + srow) * K + (sb >> 1));

  auto STAGE_A = [&](int sA, int k0) {             // 4 async16/thread
    unsigned short* s = lds + sA * ASLE;
#pragma unroll
    for (int j = 0; j < 4; ++j)
      async16(Ag + aG0 + (unsigned)(j * 32 * K + k0), s + t * 8 + j * 2048);
  };
  auto STAGE_B = [&](int sB, int k0) {             // 4 async16/thread
    unsigned short* s = lds + BOFF + sB * ASLE;
#pragma unroll
    for (int j = 0; j < 4; ++j)
      async16(Bg + bG0 + (unsigned)(j * 32 * K + k0), s + t * 8 + j * 2048);
  };

  int aRd[2][4], bRd[2][4];
#pragma unroll
  for (int kk = 0; kk < 2; ++kk)
#pragma unroll
    for (int i = 0; i < 4; ++i) {
      const int ra = wm * 64 + i * 16 + l15;
      aRd[kk][i] = (ra * 128 + ((kk * 64 + lkb) ^ ((ra & 7) << 4))) >> 1;
      const int rb = wn * 64 + i * 16 + l15;
      bRd[kk][i] = (rb * 128 + ((kk * 64 + lkb) ^ ((rb & 7) << 4))) >> 1;
    }

  const int nt = K >> 6;
  // prologue: A(0), B(0), A(1) -> 12 loads in flight
  STAGE_A(0, 0);
  STAGE_B(0, 0);
  if (nt > 1) STAGE_A(1, 64);

  int sA = 0, sA2 = 2, sB = 0;       // kt%3, (kt+2)%3, kt&1
  for (int kt = 0; kt < nt; ++kt) {
    if (kt + 1 < nt) asm volatile("s_waitcnt vmcnt(4)" ::: "memory"); // A(kt)+B(kt) done, A(kt+1) rides
    else             asm volatile("s_waitcnt vmcnt(0)" ::: "memory");
    __builtin_amdgcn_s_barrier();                  // tile kt visible; old slots' reads retired
    if (kt + 1 < nt) STAGE_B(sB ^ 1, (kt + 1) << 6);
    if (kt + 2 < nt) STAGE_A(sA2, (kt + 2) << 6);
    const unsigned short* baseA = lds + sA * ASLE;
    const unsigned short* baseB = lds + BOFF + sB * ASLE;
    // preload ALL fragments for this tile, then one 32-MFMA cluster
    bf16x8 a[2][4], b[2][4];
#pragma unroll
    for (int kk = 0; kk < 2; ++kk) {
#pragma unroll
      for (int i = 0; i < 4; ++i) a[kk][i] = *reinterpret_cast<const bf16x8*>(baseA + aRd[kk][i]);
#pragma unroll
      for (int i = 0; i < 4; ++i) b[kk][i] = *reinterpret_cast<const bf16x8*>(baseB + bRd[kk][i]);
    }
    __builtin_amdgcn_s_setprio(1);
#pragma unroll
    for (int kk = 0; kk < 2; ++kk)
#pragma unroll
      for (int mi = 0; mi < 4; ++mi)
#pragma unroll
        for (int ni = 0; ni < 4; ++ni)
          acc[mi][ni] = __builtin_amdgcn_mfma_f32_16x16x32_bf16(a[kk][mi], b[kk][ni], acc[mi][ni], 0, 0, 0);
    __builtin_amdgcn_s_setprio(0);
    sA  = (sA  == 2) ? 0 : sA  + 1;
    sA2 = (sA2 == 2) ? 0 : sA2 + 1;
    sB ^= 1;
  }
}

// ---------- recurrent layer GEMM ----------
__global__ __launch_bounds__(256, 2) void k_gemm_layer(
    const unsigned short* __restrict__ A, const unsigned short* __restrict__ W,
    const float* __restrict__ bias, float* __restrict__ preact,
    unsigned short* __restrict__ Anext)
{
  __shared__ __align__(16) unsigned short lds[5 * ASLE];   // 80 KB
  const int bid = blockIdx.x;            // 512 blocks = 16 bm x 32 bn
  const int xcd = bid & 7;
  const int idx = bid >> 3;              // 0..63
  const int bm  = (idx >> 2) * 128;      // 16 m-bands
  const int bn  = (xcd * 4 + (idx & 3)) * 128;   // XCD owns 4 bn-bands (W L2-fit)
  f32x4 acc[4][4] = {};
  gemm_core(A, W, NH, bm, bn, lds, acc);

  const int lane = threadIdx.x & 63;
  const int wave = threadIdx.x >> 6;
  const int wm = (wave >> 1) * 64, wn = (wave & 1) * 64;
  const int l15 = lane & 15;
#pragma unroll
  for (int mi = 0; mi < 4; ++mi) {
    const int gm0 = bm + wm + mi * 16 + (lane >> 4) * 4;   // C/D: row=(lane>>4)*4+r
#pragma unroll
    for (int ni = 0; ni < 4; ++ni) {
      const int gn = bn + wn + ni * 16 + l15;              // C/D: col=lane&15
      const float bv = bias[gn];
#pragma unroll
      for (int r = 0; r < 4; ++r) {
        const int gm = gm0 + r;
        const float y = acc[mi][ni][r] + bv;
        if (gm < MB) preact[(size_t)gm * NH + gn] = y;
        Anext[(size_t)gm * NH + gn] = f2bf(y > 0.f ? y : 0.f);
      }
    }
  }
}

// ---------- input GEMM ----------
__global__ __launch_bounds__(256, 2) void k_gemm_in(
    const unsigned short* __restrict__ X, const unsigned short* __restrict__ W,
    const float* __restrict__ bias, float* __restrict__ preact0,
    unsigned short* __restrict__ A0)
{
  __shared__ __align__(16) unsigned short lds[5 * ASLE];
  const int bid = blockIdx.x;            // 512 blocks = 8 bm x 64 bn
  const int xcd = bid & 7;
  const int idx = bid >> 3;              // 0..63
  const int bm  = (idx >> 3) * 128;      // 8 m-bands
  const int bn  = (xcd * 8 + (idx & 7)) * 128;
  f32x4 acc[4][4] = {};
  gemm_core(X, W, KPAD, bm, bn, lds, acc);

  const int lane = threadIdx.x & 63;
  const int wave = threadIdx.x >> 6;
  const int wm = (wave >> 1) * 64, wn = (wave & 1) * 64;
  const int l15 = lane & 15;
#pragma unroll
  for (int mi = 0; mi < 4; ++mi) {
    const int gm0 = bm + wm + mi * 16 + (lane >> 4) * 4;
#pragma unroll
    for (int ni = 0; ni < 4; ++ni) {
      const int gn = bn + wn + ni * 16 + l15;
      const float bv = bias[gn];
#pragma unroll
      for (int r = 0; r < 4; ++r) {
        const int gm = gm0 + r;
        const float y = acc[mi][ni][r] + bv;
        const unsigned short rl = f2bf(y > 0.f ? y : 0.f);
        if (gn < NH) {                       // "a" stream
          preact0[(size_t)gm * NH + gn] = y;
          A0[(size_t)gm * NH + gn] = rl;
        } else {                             // "b" stream -> rows 1024..2047
          A0[(size_t)(MB + gm) * NH + (gn - NH)] = rl;
        }
      }
    }
  }
}

// ---------- final head: 256 blocks x 8 rows, vectorized loads ----------
__global__ __launch_bounds__(256) void k_final(
    const unsigned short* __restrict__ A, const float* __restrict__ Wf,
    const float* __restrict__ of, const float* __restrict__ bf_,
    float* __restrict__ out)
{
  __shared__ float red[4][NOUT];
  const int t = threadIdx.x;
  for (int rr = 0; rr < 8; ++rr) {
    const int m = blockIdx.x * 8 + rr;          // 0..2047
    float accj[NOUT];
#pragma unroll
    for (int j = 0; j < NOUT; ++j) accj[j] = 0.f;
    for (int k0 = t * 8; k0 < NH; k0 += 256 * 8) {
      const ushort8v av = *reinterpret_cast<const ushort8v*>(A + (size_t)m * NH + k0);
      const float4 o0 = *reinterpret_cast<const float4*>(of + k0);
      const float4 o1 = *reinterpret_cast<const float4*>(of + k0 + 4);
      float a[8];
      a[0] = bf2f(av[0]) * o0.x; a[1] = bf2f(av[1]) * o0.y;
      a[2] = bf2f(av[2]) * o0.z; a[3] = bf2f(av[3]) * o0.w;
      a[4] = bf2f(av[4]) * o1.x; a[5] = bf2f(av[5]) * o1.y;
      a[6] = bf2f(av[6]) * o1.z; a[7] = bf2f(av[7]) * o1.w;
#pragma unroll
      for (int j = 0; j < NOUT; ++j) {
        const float4 w0 = *reinterpret_cast<const float4*>(Wf + (size_t)j * NH + k0);
        const float4 w1 = *reinterpret_cast<const float4*>(Wf + (size_t)j * NH + k0 + 4);
        accj[j] += a[0]*w0.x + a[1]*w0.y + a[2]*w0.z + a[3]*w0.w
                 + a[4]*w1.x + a[5]*w1.y + a[6]*w1.z + a[7]*w1.w;
      }
    }
#pragma unroll
    for (int j = 0; j < NOUT; ++j) {
      float v = accj[j];
      for (int off = 32; off > 0; off >>= 1) v += __shfl_down(v, off);
      if ((t & 63) == 0) red[t >> 6][j] = v;
    }
    __syncthreads();
    if (t < NOUT)
      out[(size_t)m * NOUT + t] = red[0][t] + red[1][t] + red[2][t] + red[3][t] + bf_[t];
    __syncthreads();
  }
}

extern "C" void kernel_launch(void* const* d_in, const int* in_sizes, int n_in,
                              void* d_out, int out_size, void* d_ws, size_t ws_size,
                              hipStream_t stream) {
  const float* x     = (const float*)d_in[0];
  const float* W_in  = (const float*)d_in[1];
  const float* b_in  = (const float*)d_in[2];
  const float* keysp = (const float*)d_in[3];
  const float* W_sp  = (const float*)d_in[4];
  const float* b_sp  = (const float*)d_in[5];
  const float* keyf  = (const float*)d_in[6];
  const float* W_f   = (const float*)d_in[7];
  const float* b_f   = (const float*)d_in[8];

  float* out    = (float*)d_out;
  float* preact = out + (size_t)2 * MB * NOUT;  // 25 x 1024 x 4096

  char* ws = (char*)d_ws;
  unsigned short* Wsp_bf = (unsigned short*)ws;  ws += (size_t)NH * NH * 2;
  unsigned short* A0     = (unsigned short*)ws;  ws += (size_t)M2 * NH * 2;
  unsigned short* A1     = (unsigned short*)ws;  ws += (size_t)M2 * NH * 2;
  unsigned short* Win_bf = (unsigned short*)ws;  ws += (size_t)N_IN * KPAD * 2;
  unsigned short* X_bf   = (unsigned short*)ws;  ws += (size_t)MB * KPAD * 2;

  k_conv_wsp<<<(NH * (size_t)NH / 4 + 255) / 256, 256, 0, stream>>>(W_sp, keysp, Wsp_bf);
  k_conv_pad2<<<((size_t)(N_IN + MB) * KPAD + 255) / 256, 256, 0, stream>>>(
      W_in, x, Win_bf, X_bf);

  // input GEMM: M=1024, N=8192, K=832 -> 8*64 = 512 blocks
  k_gemm_in<<<512, 256, 0, stream>>>(X_bf, Win_bf, b_in, preact, A0);

  // 24 recurrent layers: M=2048, N=4096, K=4096 -> 16*32 = 512 blocks
  unsigned short* Ain = A0;
  unsigned short* Aout = A1;
  for (int tlay = 0; tlay < NLAYERS; ++tlay) {
    float* pre = preact + (size_t)(tlay + 1) * MB * NH;
    k_gemm_layer<<<512, 256, 0, stream>>>(Ain, Wsp_bf, b_sp, pre, Aout);
    unsigned short* tmp = Ain; Ain = Aout; Aout = tmp;
  }

  k_final<<<M2 / 8, 256, 0, stream>>>(Ain, W_f, keyf, b_f, out);
}